// Round 24
// baseline (801.790 us; speedup 1.0000x reference)
//
#include <hip/hip_runtime.h>
#include <math.h>

#define B_ 1024
#define S_ 50
#define D_ 96
#define H_ 8
#define DH_ 12
#define DF_ 192
#define L_ 3
#define NC_ 3
#define V_ 40000
#define SR_ 4      // k_step rows per block (256 blocks = 1/CU) — R12-measured best

#define SCR_L 14745600ull   // per-layer scratch floats (51200*288)
#define KV_L  9830400ull    // per-layer kv floats (51200*192)

typedef __attribute__((ext_vector_type(8))) short short8v;   // 8 bf16 (4 VGPRs)
typedef __attribute__((ext_vector_type(4))) float float4v;   // 4 fp32 acc

__device__ __forceinline__ float dot4f(float4 a, float4 b) {
  return a.x*b.x + a.y*b.y + a.z*b.z + a.w*b.w;
}
__device__ __forceinline__ float geluf(float v) {
  return 0.5f*v*(1.0f + erff(v*0.70710678118654752f));
}
__device__ __forceinline__ unsigned short f2bf(float f) {
  unsigned int b = __float_as_uint(f);
  return (unsigned short)((b + 0x7FFFu + ((b >> 16) & 1u)) >> 16);
}

// ---------------- embedding ----------------
__global__ void k_embed(const int* __restrict__ loc, const int* __restrict__ users,
                        const int* __restrict__ mins, const int* __restrict__ wd,
                        const float* __restrict__ loc_emb, const float* __restrict__ user_emb,
                        const float* __restrict__ hour_emb, const float* __restrict__ wd_emb,
                        const float* __restrict__ temp_w, const float* __restrict__ temp_b,
                        const float* __restrict__ pos, float* __restrict__ x)
{
  int bs = blockIdx.x; int b = bs / S_; int s = bs % S_;
  __shared__ float tmp[48];
  int t = threadIdx.x;
  if (t < 48) {
    int hr = (mins[bs] / 60) % 24;
    int w  = wd[bs];
    tmp[t] = (t < 24) ? hour_emb[hr*24 + t] : wd_emb[w*24 + (t-24)];
  }
  __syncthreads();
  int lc = loc[bs]; int u = users[b*S_];
  float acc = temp_b[t] + loc_emb[(size_t)lc*D_ + t] + user_emb[(size_t)u*D_ + t] + pos[s*D_ + t];
  const float* twr = temp_w + t*48;
  #pragma unroll
  for (int k = 0; k < 48; k++) acc += tmp[k] * twr[k];
  x[(size_t)bs*D_ + t] = acc;
}

// ---------------- init hidden ----------------
__global__ void k_init(const float* __restrict__ init_hidden, float* __restrict__ hidden) {
  int i = blockIdx.x*256 + threadIdx.x;
  if (i < B_*D_) hidden[i] = init_hidden[i % D_];
}

// ---------------- fp32 -> bf16 (RNE) ----------------
__global__ void k_tobf16(const float* __restrict__ in, unsigned short* __restrict__ out, int n) {
  int i = blockIdx.x*256 + threadIdx.x;
  if (i < n) out[i] = f2bf(in[i]);
}

// ---- strided: attn-out (scratch cols 0..95, lda 288) -> bf16 at ushort-offset 192 ----
__global__ void k_tobf16_attn(float* __restrict__ scratch_base) {
  float* scr = scratch_base + (size_t)blockIdx.y*SCR_L;
  int idx = blockIdx.x*256 + threadIdx.x;   // < 51200*96
  int row = idx / 96, col = idx % 96;
  float v = scr[(size_t)row*288 + col];
  ((unsigned short*)scr)[(size_t)row*576 + 192 + col] = f2bf(v);
}

// ---------------- QKV GEMM via bf16 MFMA (R21-validated) ----------------
__global__ __launch_bounds__(256) void k_qkv_mfma(const unsigned short* __restrict__ xb,
                                                  const unsigned short* __restrict__ wib,
                                                  const float* __restrict__ bi_b,
                                                  float* __restrict__ qkv)
{
  int l = blockIdx.y;
  const unsigned short* wi = wib + (size_t)l*288*96;
  const float* bi = bi_b + (size_t)l*288;
  float* out = qkv + (size_t)l*SCR_L;

  int tid = threadIdx.x;
  int wv = tid >> 6, lane = tid & 63;
  int c = lane & 15, g = lane >> 4;
  int row0 = blockIdx.x*64 + wv*16;

  short8v afrag[3];
  const unsigned short* arow = xb + (size_t)(row0 + c)*96 + g*8;
  #pragma unroll
  for (int kc = 0; kc < 3; kc++) afrag[kc] = *(const short8v*)&arow[kc*32];

  for (int ct = 0; ct < 18; ct++) {
    int col0 = ct*16;
    short8v bfrag[3];
    const unsigned short* wrow = wi + (size_t)(col0 + c)*96 + g*8;
    #pragma unroll
    for (int kc = 0; kc < 3; kc++) bfrag[kc] = *(const short8v*)&wrow[kc*32];
    float4v acc = {0.f, 0.f, 0.f, 0.f};
    #pragma unroll
    for (int kc = 0; kc < 3; kc++)
      acc = __builtin_amdgcn_mfma_f32_16x16x32_bf16(afrag[kc], bfrag[kc], acc, 0, 0, 0);
    float bj = bi[col0 + c];
    #pragma unroll
    for (int reg = 0; reg < 4; reg++)
      out[(size_t)(row0 + g*4 + reg)*288 + col0 + c] = acc[reg] + bj;
  }
}

// ---------------- attention: stride-48 LDS, float4 reads, ONLINE softmax (no p[] array) ----
__global__ __launch_bounds__(256) void k_attn3(float* __restrict__ qkv)
{
  qkv += (size_t)blockIdx.y*SCR_L;
  __shared__ __align__(16) float q_s[S_*48], k_s[S_*48], v_s[S_*48];
  int tid = threadIdx.x;
  int bh = blockIdx.x; int b = bh >> 1, h4 = bh & 1;
  size_t base = (size_t)b*S_*288 + h4*48;

  for (int idx = tid; idx < 3*S_*12; idx += 256) {
    int m = idx / 600, rem = idx % 600, s = rem / 12, f = rem % 12;
    float4 v = *(const float4*)&qkv[base + (size_t)s*288 + m*96 + 4*f];
    float* dst = (m == 0) ? q_s : (m == 1) ? k_s : v_s;
    *(float4*)&dst[s*48 + 4*f] = v;
  }
  __syncthreads();
  if (tid < 4*S_) {
    int hh = tid / S_, i = tid % S_;
    int hb = hh*12;
    float4 q0 = *(float4*)&q_s[i*48 + hb];
    float4 q1 = *(float4*)&q_s[i*48 + hb + 4];
    float4 q2 = *(float4*)&q_s[i*48 + hb + 8];
    float m = -1e30f, sum = 0.f;
    float4 o0 = {0.f,0.f,0.f,0.f}, o1 = {0.f,0.f,0.f,0.f}, o2 = {0.f,0.f,0.f,0.f};
    for (int s = 0; s < S_; s++) {
      const float* kr = &k_s[s*48 + hb];
      float4 k0 = *(const float4*)&kr[0];
      float4 k1 = *(const float4*)&kr[4];
      float4 k2 = *(const float4*)&kr[8];
      float acc = (dot4f(q0, k0) + dot4f(q1, k1) + dot4f(q2, k2)) * 0.28867513459481287f;
      float mnew = fmaxf(m, acc);
      float corr = expf(m - mnew);     // first iter: exp(-inf) = 0
      float p = expf(acc - mnew);
      sum = sum*corr + p;
      const float* vr = &v_s[s*48 + hb];
      float4 v0 = *(const float4*)&vr[0];
      float4 v1 = *(const float4*)&vr[4];
      float4 v2 = *(const float4*)&vr[8];
      o0.x = o0.x*corr + p*v0.x; o0.y = o0.y*corr + p*v0.y;
      o0.z = o0.z*corr + p*v0.z; o0.w = o0.w*corr + p*v0.w;
      o1.x = o1.x*corr + p*v1.x; o1.y = o1.y*corr + p*v1.y;
      o1.z = o1.z*corr + p*v1.z; o1.w = o1.w*corr + p*v1.w;
      o2.x = o2.x*corr + p*v2.x; o2.y = o2.y*corr + p*v2.y;
      o2.z = o2.z*corr + p*v2.z; o2.w = o2.w*corr + p*v2.w;
      m = mnew;
    }
    float inv = 1.f / sum;
    float* orow = qkv + (size_t)(b*S_ + i)*288 + h4*48 + hb;
    o0.x *= inv; o0.y *= inv; o0.z *= inv; o0.w *= inv;
    o1.x *= inv; o1.y *= inv; o1.z *= inv; o1.w *= inv;
    o2.x *= inv; o2.y *= inv; o2.z *= inv; o2.w *= inv;
    *(float4*)&orow[0] = o0;
    *(float4*)&orow[4] = o1;
    *(float4*)&orow[8] = o2;
  }
}

// ---------------- Wo-proj via bf16 MFMA + residual epilogue -> preLN (cols 144..239) ----
__global__ __launch_bounds__(256) void k_wo_mfma(float* __restrict__ scratch_base,
                                                 const unsigned short* __restrict__ wo_b,
                                                 const float* __restrict__ bo_b,
                                                 const float* __restrict__ x)
{
  int l = blockIdx.y;
  float* scr = scratch_base + (size_t)l*SCR_L;
  const unsigned short* Ab = (const unsigned short*)scr;   // row stride 576, offset 192
  const unsigned short* wb = wo_b + (size_t)l*96*96;
  const float* bo = bo_b + (size_t)l*96;

  int tid = threadIdx.x;
  int wv = tid >> 6, lane = tid & 63;
  int c = lane & 15, g = lane >> 4;
  int row0 = blockIdx.x*64 + wv*16;

  short8v afrag[3];
  const unsigned short* arow = Ab + (size_t)(row0 + c)*576 + 192 + g*8;
  #pragma unroll
  for (int kc = 0; kc < 3; kc++) afrag[kc] = *(const short8v*)&arow[kc*32];

  for (int ct = 0; ct < 6; ct++) {
    int col0 = ct*16;
    short8v bfrag[3];
    const unsigned short* wrow = wb + (size_t)(col0 + c)*96 + g*8;
    #pragma unroll
    for (int kc = 0; kc < 3; kc++) bfrag[kc] = *(const short8v*)&wrow[kc*32];
    float4v acc = {0.f, 0.f, 0.f, 0.f};
    #pragma unroll
    for (int kc = 0; kc < 3; kc++)
      acc = __builtin_amdgcn_mfma_f32_16x16x32_bf16(afrag[kc], bfrag[kc], acc, 0, 0, 0);
    float bj = bo[col0 + c];
    #pragma unroll
    for (int reg = 0; reg < 4; reg++) {
      int row = row0 + g*4 + reg;
      scr[(size_t)row*288 + 144 + col0 + c] = acc[reg] + bj + x[(size_t)row*96 + col0 + c];
    }
  }
}

// ---------------- LN(n1) over preLN (cols 144..239) -> normalized bf16 (ushort 480..575) ----
__global__ __launch_bounds__(256) void k_lnbf16(float* __restrict__ scratch_base,
                                                const float* __restrict__ n1g_b,
                                                const float* __restrict__ n1b_b)
{
  int l = blockIdx.y;
  float* scr = scratch_base + (size_t)l*SCR_L;
  const float* g = n1g_b + (size_t)l*96;
  const float* bb = n1b_b + (size_t)l*96;
  int row = blockIdx.x*4 + (threadIdx.x >> 6);
  int t = threadIdx.x & 63;
  const float* in = scr + (size_t)row*288 + 144;
  float e0 = in[t];
  float e1 = (t < 32) ? in[64 + t] : 0.f;
  float s = e0 + e1;
  for (int off = 32; off > 0; off >>= 1) s += __shfl_xor(s, off, 64);
  float mean = s * (1.f/96.f);
  float d0 = e0 - mean;
  float d1 = (t < 32) ? (e1 - mean) : 0.f;
  float v = d0*d0 + d1*d1;
  for (int off = 32; off > 0; off >>= 1) v += __shfl_xor(v, off, 64);
  float rstd = rsqrtf(v*(1.f/96.f) + 1e-5f);
  unsigned short* outp = (unsigned short*)scr + (size_t)row*576 + 480;
  outp[t] = f2bf(d0*rstd*g[t] + bb[t]);
  if (t < 32) outp[64 + t] = f2bf(d1*rstd*g[64 + t] + bb[64 + t]);
}

// ---------------- KV-proj via bf16 MFMA: normalized bf16 -> kv fp32 ----------------
__global__ __launch_bounds__(256) void k_kv_mfma(const float* __restrict__ scratch_base,
                                                 const unsigned short* __restrict__ kwi_full, // [3][288][96] bf16
                                                 const float* __restrict__ ci_bi_b,
                                                 float* __restrict__ kv_base)
{
  int l = blockIdx.y;
  const float* scr = scratch_base + (size_t)l*SCR_L;
  const unsigned short* Ab = (const unsigned short*)scr;   // row stride 576, offset 480
  const unsigned short* kwi = kwi_full + (size_t)l*288*96 + 96*96;
  const float* kbi = ci_bi_b + (size_t)l*288 + 96;
  float* out = kv_base + (size_t)l*KV_L;

  int tid = threadIdx.x;
  int wv = tid >> 6, lane = tid & 63;
  int c = lane & 15, g = lane >> 4;
  int row0 = blockIdx.x*64 + wv*16;

  short8v afrag[3];
  const unsigned short* arow = Ab + (size_t)(row0 + c)*576 + 480 + g*8;
  #pragma unroll
  for (int kc = 0; kc < 3; kc++) afrag[kc] = *(const short8v*)&arow[kc*32];

  for (int ct = 0; ct < 12; ct++) {
    int col0 = ct*16;
    short8v bfrag[3];
    const unsigned short* wrow = kwi + (size_t)(col0 + c)*96 + g*8;
    #pragma unroll
    for (int kc = 0; kc < 3; kc++) bfrag[kc] = *(const short8v*)&wrow[kc*32];
    float4v acc = {0.f, 0.f, 0.f, 0.f};
    #pragma unroll
    for (int kc = 0; kc < 3; kc++)
      acc = __builtin_amdgcn_mfma_f32_16x16x32_bf16(afrag[kc], bfrag[kc], acc, 0, 0, 0);
    float bj = kbi[col0 + c];
    #pragma unroll
    for (int reg = 0; reg < 4; reg++)
      out[(size_t)(row0 + g*4 + reg)*192 + col0 + c] = acc[reg] + bj;
  }
}

// ---------------- tiled GEMM (head1 only) ----------------
template<int ACT>
__global__ __launch_bounds__(256) void k_gemm96(const float* __restrict__ A,
                                                const float* __restrict__ W,
                                                const float* __restrict__ bias,
                                                float* __restrict__ out,
                                                int nrows, int out_dim)
{
  __shared__ __align__(16) float a_s[32*100];
  __shared__ __align__(16) float w_s[128*100];
  __shared__ float b_s[128];
  int tid = threadIdx.x;
  int row0 = blockIdx.x*32, col0 = blockIdx.y*128;
  for (int idx = tid; idx < 32*24; idx += 256) {
    int r = idx/24, q = idx%24;
    *(float4*)&a_s[r*100 + q*4] = *(const float4*)&A[(size_t)(row0+r)*96 + q*4];
  }
  for (int idx = tid; idx < 128*24; idx += 256) {
    int j = idx/24, q = idx%24;
    int jj = col0 + j;
    float4 w;
    if (jj < out_dim) w = *(const float4*)&W[(size_t)jj*96 + q*4];
    else { w.x = w.y = w.z = w.w = 0.f; }
    *(float4*)&w_s[j*100 + q*4] = w;
  }
  if (tid < 128) b_s[tid] = (col0 + tid < out_dim) ? bias[col0 + tid] : 0.f;
  __syncthreads();
  int tc = tid % 32, tr = tid / 32;
  int r0 = tr*4;
  float acc[4][4];
  #pragma unroll
  for (int cc = 0; cc < 4; cc++) {
    float bv = b_s[tc + 32*cc];
    #pragma unroll
    for (int rr = 0; rr < 4; rr++) acc[rr][cc] = bv;
  }
  #pragma unroll
  for (int d = 0; d < 96; d += 4) {
    float4 a4[4], w4[4];
    #pragma unroll
    for (int rr = 0; rr < 4; rr++) a4[rr] = *(float4*)&a_s[(r0+rr)*100 + d];
    #pragma unroll
    for (int cc = 0; cc < 4; cc++) w4[cc] = *(float4*)&w_s[(tc + 32*cc)*100 + d];
    #pragma unroll
    for (int rr = 0; rr < 4; rr++)
      #pragma unroll
      for (int cc = 0; cc < 4; cc++)
        acc[rr][cc] += dot4f(a4[rr], w4[cc]);
  }
  #pragma unroll
  for (int rr = 0; rr < 4; rr++) {
    int row = row0 + r0 + rr;
    float* orow = out + (size_t)row*out_dim + col0;
    #pragma unroll
    for (int cc = 0; cc < 4; cc++) {
      int j = tc + 32*cc;
      if (col0 + j < out_dim) {
        float v = acc[rr][cc];
        if (ACT == 1) v = geluf(v);
        orow[j] = v;
      }
    }
  }
}

// ---------------- logits GEMM via bf16 MFMA (R20-validated) ----------------
__global__ __launch_bounds__(256) void k_logits_mfma(const unsigned short* __restrict__ Ab,
                                                     const unsigned short* __restrict__ Wb,
                                                     const float* __restrict__ bias,
                                                     float* __restrict__ out)
{
  int tid = threadIdx.x;
  int wv = tid >> 6, lane = tid & 63;
  int col0 = blockIdx.x*64 + wv*16;
  int c = lane & 15, g = lane >> 4;

  short8v bfrag[3];
  const unsigned short* wrow = Wb + (size_t)(col0 + c)*96 + g*8;
  #pragma unroll
  for (int kc = 0; kc < 3; kc++)
    bfrag[kc] = *(const short8v*)&wrow[kc*32];
  float bj = bias[col0 + c];

  for (int rt = 0; rt < 64; rt++) {
    const unsigned short* arow = Ab + (size_t)(rt*16 + c)*96 + g*8;
    float4v acc = {0.f, 0.f, 0.f, 0.f};
    #pragma unroll
    for (int kc = 0; kc < 3; kc++) {
      short8v afrag = *(const short8v*)&arow[kc*32];
      acc = __builtin_amdgcn_mfma_f32_16x16x32_bf16(afrag, bfrag[kc], acc, 0, 0, 0);
    }
    int row = rt*16 + g*4;
    #pragma unroll
    for (int reg = 0; reg < 4; reg++)
      out[(size_t)(row + reg)*V_ + col0 + c] = acc[reg] + bj;
  }
}

// ---------------- one full recurrent step, SR_ batch rows per block (R12 proven) ----------------
__global__ __launch_bounds__(256) void k_step(float* __restrict__ hidden,
    const float* __restrict__ kv_l,
    const float* __restrict__ ci_wi, const float* __restrict__ ci_bi,
    const float* __restrict__ ci_wo, const float* __restrict__ ci_bo,
    const float* __restrict__ ch_wi, const float* __restrict__ ch_bi,
    const float* __restrict__ ch_wo, const float* __restrict__ ch_bo,
    const float* __restrict__ gw, const float* __restrict__ gb,
    const float* __restrict__ w1, const float* __restrict__ b1,
    const float* __restrict__ w2, const float* __restrict__ b2,
    const float* __restrict__ n2g, const float* __restrict__ n2b,
    const float* __restrict__ n3g, const float* __restrict__ n3b)
{
  __shared__ __align__(16) float hs[SR_][100];
  __shared__ __align__(16) float bufA[SR_][100];
  __shared__ __align__(16) float bufB[SR_][100];
  __shared__ __align__(16) float bufC[SR_][100];
  __shared__ __align__(16) float f1b[SR_][200];
  int tid = threadIdx.x; int b0 = blockIdx.x*SR_;

  for (int idx = tid; idx < SR_*24; idx += 256) {
    int r = idx/24, q = idx%24;
    *(float4*)&hs[r][q*4] = *(const float4*)&hidden[(size_t)(b0+r)*96 + q*4];
  }
  __syncthreads();

  for (int idx = tid; idx < SR_*192; idx += 256) {
    int r = idx % SR_, j = idx / SR_;
    const float* wr = (j < 96) ? (ci_wi + (size_t)j*96) : (ch_wi + (size_t)(96 + j)*96);
    float acc = (j < 96) ? ci_bi[j] : ch_bi[96 + j];
    #pragma unroll
    for (int d = 0; d < 96; d += 4) {
      float4 a = *(float4*)&hs[r][d];
      float4 w = *(const float4*)&wr[d];
      acc += dot4f(a, w);
    }
    if (j < 96) bufA[r][j] = acc; else bufB[r][j-96] = acc;
  }
  __syncthreads();

  if (tid < SR_*8) {
    int r = tid >> 3, h = tid & 7;
    int b = b0 + r;
    float q[12];
    #pragma unroll
    for (int d = 0; d < 12; d++) q[d] = bufA[r][h*12 + d];
    float p[50]; float mx = -1e30f;
    for (int s = 0; s < 50; s++) {
      const float* kr = kv_l + ((size_t)(b*50 + s))*192 + h*12;
      float4 k0 = *(const float4*)&kr[0];
      float4 k1 = *(const float4*)&kr[4];
      float4 k2 = *(const float4*)&kr[8];
      float acc = q[0]*k0.x + q[1]*k0.y + q[2]*k0.z + q[3]*k0.w
                + q[4]*k1.x + q[5]*k1.y + q[6]*k1.z + q[7]*k1.w
                + q[8]*k2.x + q[9]*k2.y + q[10]*k2.z + q[11]*k2.w;
      acc *= 0.28867513459481287f;
      p[s] = acc; mx = fmaxf(mx, acc);
    }
    float sum = 0.f;
    for (int s = 0; s < 50; s++) { p[s] = expf(p[s] - mx); sum += p[s]; }
    float inv = 1.f / sum;
    float o[12];
    #pragma unroll
    for (int d = 0; d < 12; d++) o[d] = 0.f;
    for (int s = 0; s < 50; s++) {
      const float* vr = kv_l + ((size_t)(b*50 + s))*192 + 96 + h*12;
      float4 v0 = *(const float4*)&vr[0];
      float4 v1 = *(const float4*)&vr[4];
      float4 v2 = *(const float4*)&vr[8];
      float pv = p[s];
      o[0] += pv*v0.x; o[1] += pv*v0.y; o[2]  += pv*v0.z; o[3]  += pv*v0.w;
      o[4] += pv*v1.x; o[5] += pv*v1.y; o[6]  += pv*v1.z; o[7]  += pv*v1.w;
      o[8] += pv*v2.x; o[9] += pv*v2.y; o[10] += pv*v2.z; o[11] += pv*v2.w;
    }
    #pragma unroll
    for (int d = 0; d < 12; d++) bufC[r][h*12 + d] = o[d]*inv;
  }
  __syncthreads();

  for (int idx = tid; idx < SR_*192; idx += 256) {
    int r = idx % SR_, j = idx / SR_;
    int jj = (j < 96) ? j : (j - 96);
    const float* ar = (j < 96) ? bufC[r] : bufB[r];
    const float* wr = ((j < 96) ? ci_wo : ch_wo) + (size_t)jj*96;
    float acc = (j < 96) ? ci_bo[jj] : ch_bo[jj];
    #pragma unroll
    for (int d = 0; d < 96; d += 4) {
      float4 a = *(float4*)&ar[d];
      float4 w = *(const float4*)&wr[d];
      acc += dot4f(a, w);
    }
    if (j < 96) bufA[r][j] = acc; else f1b[r][jj] = acc;
  }
  __syncthreads();

  for (int idx = tid; idx < SR_*96; idx += 256) {
    int r = idx % SR_, j = idx / SR_;
    const float* gr = gw + (size_t)j*192;
    float acc = gb[j];
    #pragma unroll
    for (int d = 0; d < 96; d += 4) {
      float4 c1v = *(float4*)&bufA[r][d];
      float4 g1 = *(const float4*)&gr[d];
      float4 c2v = *(float4*)&f1b[r][d];
      float4 g2 = *(const float4*)&gr[96 + d];
      acc += dot4f(c1v, g1) + dot4f(c2v, g2);
    }
    float gv = 1.f/(1.f + expf(-acc));
    float pre = gv*bufA[r][j] + (1.f - gv)*f1b[r][j] + hs[r][j];
    bufB[r][j] = pre;
  }
  __syncthreads();
  if (tid < SR_*16) {
    int r = tid / 16, l16 = tid % 16;
    float s1 = 0.f, s2 = 0.f;
    #pragma unroll
    for (int e = 0; e < 6; e++) { float v = bufB[r][l16*6 + e]; s1 += v; s2 += v*v; }
    for (int off = 8; off > 0; off >>= 1) { s1 += __shfl_xor(s1, off, 16); s2 += __shfl_xor(s2, off, 16); }
    float mean = s1*(1.f/96.f);
    float var = s2*(1.f/96.f) - mean*mean;
    float rstd = rsqrtf(var + 1e-5f);
    #pragma unroll
    for (int e = 0; e < 6; e++) {
      int j = l16*6 + e;
      bufB[r][j] = (bufB[r][j] - mean)*rstd*n2g[j] + n2b[j];
    }
  }
  __syncthreads();

  for (int idx = tid; idx < SR_*192; idx += 256) {
    int r = idx % SR_, j = idx / SR_;
    const float* wr = w1 + (size_t)j*96;
    float acc = b1[j];
    #pragma unroll
    for (int d = 0; d < 96; d += 4) {
      float4 a = *(float4*)&bufB[r][d];
      float4 w = *(const float4*)&wr[d];
      acc += dot4f(a, w);
    }
    f1b[r][j] = geluf(acc);
  }
  __syncthreads();

  for (int idx = tid; idx < SR_*96; idx += 256) {
    int r = idx % SR_, j = idx / SR_;
    const float* wr = w2 + (size_t)j*192;
    float acc = b2[j];
    #pragma unroll
    for (int d = 0; d < 192; d += 4) {
      float4 a = *(float4*)&f1b[r][d];
      float4 w = *(const float4*)&wr[d];
      acc += dot4f(a, w);
    }
    bufC[r][j] = acc + bufB[r][j];
  }
  __syncthreads();
  if (tid < SR_*16) {
    int r = tid / 16, l16 = tid % 16;
    float s1 = 0.f, s2 = 0.f;
    #pragma unroll
    for (int e = 0; e < 6; e++) { float v = bufC[r][l16*6 + e]; s1 += v; s2 += v*v; }
    for (int off = 8; off > 0; off >>= 1) { s1 += __shfl_xor(s1, off, 16); s2 += __shfl_xor(s2, off, 16); }
    float mean = s1*(1.f/96.f);
    float var = s2*(1.f/96.f) - mean*mean;
    float rstd = rsqrtf(var + 1e-5f);
    #pragma unroll
    for (int e = 0; e < 6; e++) {
      int j = l16*6 + e;
      hidden[(size_t)(b0 + r)*96 + j] = (bufC[r][j] - mean)*rstd*n3g[j] + n3b[j];
    }
  }
}

extern "C" void kernel_launch(void* const* d_in, const int* in_sizes, int n_in,
                              void* d_out, int out_size, void* d_ws, size_t ws_size,
                              hipStream_t stream) {
  (void)in_sizes; (void)n_in; (void)out_size; (void)ws_size;
  const int* locations   = (const int*)d_in[0];
  const int* users       = (const int*)d_in[1];
  const int* start_mins  = (const int*)d_in[2];
  const int* weekdays    = (const int*)d_in[3];
  const float* loc_emb   = (const float*)d_in[4];
  const float* user_emb  = (const float*)d_in[5];
  const float* hour_emb  = (const float*)d_in[6];
  const float* wd_emb    = (const float*)d_in[7];
  const float* temp_w    = (const float*)d_in[8];
  const float* temp_b    = (const float*)d_in[9];
  const float* pos_embed = (const float*)d_in[10];
  const float* init_hidden = (const float*)d_in[11];
  const float* out_w1    = (const float*)d_in[12];
  const float* out_b1    = (const float*)d_in[13];
  const float* out_w2    = (const float*)d_in[14];
  const float* out_b2    = (const float*)d_in[15];
  const float* sa_wi = (const float*)d_in[16];
  const float* sa_bi = (const float*)d_in[17];
  const float* sa_wo = (const float*)d_in[18];
  const float* sa_bo = (const float*)d_in[19];
  const float* ci_wi = (const float*)d_in[20];
  const float* ci_bi = (const float*)d_in[21];
  const float* ci_wo = (const float*)d_in[22];
  const float* ci_bo = (const float*)d_in[23];
  const float* ch_wi = (const float*)d_in[24];
  const float* ch_bi = (const float*)d_in[25];
  const float* ch_wo = (const float*)d_in[26];
  const float* ch_bo = (const float*)d_in[27];
  const float* ffn_w1 = (const float*)d_in[28];
  const float* ffn_b1 = (const float*)d_in[29];
  const float* ffn_w2 = (const float*)d_in[30];
  const float* ffn_b2 = (const float*)d_in[31];
  const float* gate_w = (const float*)d_in[32];
  const float* gate_b = (const float*)d_in[33];
  const float* n1_g = (const float*)d_in[34];
  const float* n1_b = (const float*)d_in[35];
  const float* n2_g = (const float*)d_in[36];
  const float* n2_b = (const float*)d_in[37];
  const float* n3_g = (const float*)d_in[38];
  const float* n3_b = (const float*)d_in[39];

  float* ws = (float*)d_ws;
  float* x       = ws;                           // 4,915,200
  float* scratch = x + 4915200;                  // 3 * 14,745,600 (dead after phase A)
  float* kv      = scratch + 3ull*SCR_L;         // 29,491,200
  float* hidden  = kv + 29491200;                // 98,304
  float* h1      = hidden + 98304;               // 98,304

  // bf16 staging: x/sa_wi in kv region (dead until k_kv_mfma writes kv — consumed before)
  unsigned short* xb2 = (unsigned short*)kv;               // 4,915,200 bf16
  unsigned short* wib = xb2 + 4915200;                     // 3*288*96 bf16
  // small weight stages in h1 region (dead until head)
  unsigned short* wo_b  = (unsigned short*)h1;             // 3*96*96 = 27,648 bf16
  unsigned short* kwi_b = wo_b + 27648;                    // 3*288*96 = 82,944 bf16
  // head bf16 staging in scratch region (dead after phase A)
  unsigned short* h1b = (unsigned short*)scratch;          // 98,304 bf16
  unsigned short* w2b = h1b + 98304;                       // 3,840,000 bf16

  k_embed<<<B_*S_, 96, 0, stream>>>(locations, users, start_mins, weekdays,
                                    loc_emb, user_emb, hour_emb, wd_emb,
                                    temp_w, temp_b, pos_embed, x);
  k_init<<<(B_*D_ + 255)/256, 256, 0, stream>>>(init_hidden, hidden);

  // Phase A (all layers batched via blockIdx.y, full MFMA pipeline)
  k_tobf16<<<(B_*S_*D_ + 255)/256, 256, 0, stream>>>(x, xb2, B_*S_*D_);
  k_tobf16<<<(3*288*96 + 255)/256, 256, 0, stream>>>(sa_wi, wib, 3*288*96);
  k_tobf16<<<(3*96*96 + 255)/256, 256, 0, stream>>>(sa_wo, wo_b, 3*96*96);
  k_tobf16<<<(3*288*96 + 255)/256, 256, 0, stream>>>(ci_wi, kwi_b, 3*288*96);
  k_qkv_mfma<<<dim3(800, 3), 256, 0, stream>>>(xb2, wib, sa_bi, scratch);
  k_attn3<<<dim3(2048, 3), 256, 0, stream>>>(scratch);
  k_tobf16_attn<<<dim3(19200, 3), 256, 0, stream>>>(scratch);
  k_wo_mfma<<<dim3(800, 3), 256, 0, stream>>>(scratch, wo_b, sa_bo, x);
  k_lnbf16<<<dim3(12800, 3), 256, 0, stream>>>(scratch, n1_g, n1_b);
  k_kv_mfma<<<dim3(800, 3), 256, 0, stream>>>(scratch, kwi_b, ci_bi, kv);

  // Phase B: 9 separate recurrent steps (R12-measured best)
  for (int c = 0; c < NC_; c++) {
    for (int l = 0; l < L_; l++) {
      k_step<<<B_/SR_, 256, 0, stream>>>(hidden, kv + (size_t)l*KV_L,
          ci_wi + (size_t)l*288*96, ci_bi + l*288,
          ci_wo + (size_t)l*96*96,  ci_bo + l*96,
          ch_wi + (size_t)l*288*96, ch_bi + l*288,
          ch_wo + (size_t)l*96*96,  ch_bo + l*96,
          gate_w + (size_t)l*96*192, gate_b + l*96,
          ffn_w1 + (size_t)l*192*96, ffn_b1 + l*192,
          ffn_w2 + (size_t)l*96*192, ffn_b2 + l*96,
          n2_g + l*96, n2_b + l*96, n3_g + l*96, n3_b + l*96);
    }
  }

  // Head: h1 (fp32) -> bf16, W2 -> bf16, logits via MFMA (R20-validated)
  k_gemm96<1><<<dim3(B_/32, 1), 256, 0, stream>>>(hidden, out_w1, out_b1, h1, B_, 96);
  k_tobf16<<<(B_*D_ + 255)/256, 256, 0, stream>>>(h1, h1b, B_*D_);
  k_tobf16<<<(V_*D_ + 255)/256, 256, 0, stream>>>(out_w2, w2b, V_*D_);
  k_logits_mfma<<<V_/64, 256, 0, stream>>>(h1b, w2b, out_b2, (float*)d_out);
}

// Round 25
// 760.936 us; speedup vs baseline: 1.0537x; 1.0537x over previous
//
#include <hip/hip_runtime.h>
#include <math.h>

#define B_ 1024
#define S_ 50
#define D_ 96
#define H_ 8
#define DH_ 12
#define DF_ 192
#define L_ 3
#define NC_ 3
#define V_ 40000
#define SR_ 4      // k_step rows per block (256 blocks = 1/CU) — R12-measured best

#define SCR_L 14745600ull   // per-layer scratch floats (51200*288)
#define KV_L  9830400ull    // per-layer kv floats (51200*192)

typedef __attribute__((ext_vector_type(8))) short short8v;   // 8 bf16 (4 VGPRs)
typedef __attribute__((ext_vector_type(4))) float float4v;   // 4 fp32 acc

__device__ __forceinline__ float dot4f(float4 a, float4 b) {
  return a.x*b.x + a.y*b.y + a.z*b.z + a.w*b.w;
}
__device__ __forceinline__ float geluf(float v) {
  return 0.5f*v*(1.0f + erff(v*0.70710678118654752f));
}
__device__ __forceinline__ unsigned short f2bf(float f) {
  unsigned int b = __float_as_uint(f);
  return (unsigned short)((b + 0x7FFFu + ((b >> 16) & 1u)) >> 16);
}

// ---------------- embedding ----------------
__global__ void k_embed(const int* __restrict__ loc, const int* __restrict__ users,
                        const int* __restrict__ mins, const int* __restrict__ wd,
                        const float* __restrict__ loc_emb, const float* __restrict__ user_emb,
                        const float* __restrict__ hour_emb, const float* __restrict__ wd_emb,
                        const float* __restrict__ temp_w, const float* __restrict__ temp_b,
                        const float* __restrict__ pos, float* __restrict__ x)
{
  int bs = blockIdx.x; int b = bs / S_; int s = bs % S_;
  __shared__ float tmp[48];
  int t = threadIdx.x;
  if (t < 48) {
    int hr = (mins[bs] / 60) % 24;
    int w  = wd[bs];
    tmp[t] = (t < 24) ? hour_emb[hr*24 + t] : wd_emb[w*24 + (t-24)];
  }
  __syncthreads();
  int lc = loc[bs]; int u = users[b*S_];
  float acc = temp_b[t] + loc_emb[(size_t)lc*D_ + t] + user_emb[(size_t)u*D_ + t] + pos[s*D_ + t];
  const float* twr = temp_w + t*48;
  #pragma unroll
  for (int k = 0; k < 48; k++) acc += tmp[k] * twr[k];
  x[(size_t)bs*D_ + t] = acc;
}

// ---------------- init hidden ----------------
__global__ void k_init(const float* __restrict__ init_hidden, float* __restrict__ hidden) {
  int i = blockIdx.x*256 + threadIdx.x;
  if (i < B_*D_) hidden[i] = init_hidden[i % D_];
}

// ---------------- fp32 -> bf16 (RNE) ----------------
__global__ void k_tobf16(const float* __restrict__ in, unsigned short* __restrict__ out, int n) {
  int i = blockIdx.x*256 + threadIdx.x;
  if (i < n) out[i] = f2bf(in[i]);
}

// ---- strided: attn-out (scratch cols 0..95, lda 288) -> bf16 at ushort-offset 192 ----
__global__ void k_tobf16_attn(float* __restrict__ scratch_base) {
  float* scr = scratch_base + (size_t)blockIdx.y*SCR_L;
  int idx = blockIdx.x*256 + threadIdx.x;   // < 51200*96
  int row = idx / 96, col = idx % 96;
  float v = scr[(size_t)row*288 + col];
  ((unsigned short*)scr)[(size_t)row*576 + 192 + col] = f2bf(v);
}

// ---------------- QKV GEMM via bf16 MFMA (R21-validated) ----------------
__global__ __launch_bounds__(256) void k_qkv_mfma(const unsigned short* __restrict__ xb,
                                                  const unsigned short* __restrict__ wib,
                                                  const float* __restrict__ bi_b,
                                                  float* __restrict__ qkv)
{
  int l = blockIdx.y;
  const unsigned short* wi = wib + (size_t)l*288*96;
  const float* bi = bi_b + (size_t)l*288;
  float* out = qkv + (size_t)l*SCR_L;

  int tid = threadIdx.x;
  int wv = tid >> 6, lane = tid & 63;
  int c = lane & 15, g = lane >> 4;
  int row0 = blockIdx.x*64 + wv*16;

  short8v afrag[3];
  const unsigned short* arow = xb + (size_t)(row0 + c)*96 + g*8;
  #pragma unroll
  for (int kc = 0; kc < 3; kc++) afrag[kc] = *(const short8v*)&arow[kc*32];

  for (int ct = 0; ct < 18; ct++) {
    int col0 = ct*16;
    short8v bfrag[3];
    const unsigned short* wrow = wi + (size_t)(col0 + c)*96 + g*8;
    #pragma unroll
    for (int kc = 0; kc < 3; kc++) bfrag[kc] = *(const short8v*)&wrow[kc*32];
    float4v acc = {0.f, 0.f, 0.f, 0.f};
    #pragma unroll
    for (int kc = 0; kc < 3; kc++)
      acc = __builtin_amdgcn_mfma_f32_16x16x32_bf16(afrag[kc], bfrag[kc], acc, 0, 0, 0);
    float bj = bi[col0 + c];
    #pragma unroll
    for (int reg = 0; reg < 4; reg++)
      out[(size_t)(row0 + g*4 + reg)*288 + col0 + c] = acc[reg] + bj;
  }
}

// ---------------- attention: stride-48 LDS, float4 reads (R23-measured best, 111.5us) ----
__global__ __launch_bounds__(256) void k_attn3(float* __restrict__ qkv)
{
  qkv += (size_t)blockIdx.y*SCR_L;
  __shared__ __align__(16) float q_s[S_*48], k_s[S_*48], v_s[S_*48];
  int tid = threadIdx.x;
  int bh = blockIdx.x; int b = bh >> 1, h4 = bh & 1;
  size_t base = (size_t)b*S_*288 + h4*48;

  for (int idx = tid; idx < 3*S_*12; idx += 256) {
    int m = idx / 600, rem = idx % 600, s = rem / 12, f = rem % 12;
    float4 v = *(const float4*)&qkv[base + (size_t)s*288 + m*96 + 4*f];
    float* dst = (m == 0) ? q_s : (m == 1) ? k_s : v_s;
    *(float4*)&dst[s*48 + 4*f] = v;
  }
  __syncthreads();
  if (tid < 4*S_) {
    int hh = tid / S_, i = tid % S_;
    int hb = hh*12;
    float4 q0 = *(float4*)&q_s[i*48 + hb];
    float4 q1 = *(float4*)&q_s[i*48 + hb + 4];
    float4 q2 = *(float4*)&q_s[i*48 + hb + 8];
    float p[S_]; float mx = -1e30f;
    for (int s = 0; s < S_; s++) {
      const float* kr = &k_s[s*48 + hb];
      float4 k0 = *(const float4*)&kr[0];
      float4 k1 = *(const float4*)&kr[4];
      float4 k2 = *(const float4*)&kr[8];
      float acc = dot4f(q0, k0) + dot4f(q1, k1) + dot4f(q2, k2);
      acc *= 0.28867513459481287f;
      p[s] = acc; mx = fmaxf(mx, acc);
    }
    float sum = 0.f;
    for (int s = 0; s < S_; s++) { p[s] = expf(p[s] - mx); sum += p[s]; }
    float inv = 1.f / sum;
    float4 o0 = {0.f,0.f,0.f,0.f}, o1 = {0.f,0.f,0.f,0.f}, o2 = {0.f,0.f,0.f,0.f};
    for (int s = 0; s < S_; s++) {
      const float* vr = &v_s[s*48 + hb];
      float4 v0 = *(const float4*)&vr[0];
      float4 v1 = *(const float4*)&vr[4];
      float4 v2 = *(const float4*)&vr[8];
      float pv = p[s];
      o0.x += pv*v0.x; o0.y += pv*v0.y; o0.z += pv*v0.z; o0.w += pv*v0.w;
      o1.x += pv*v1.x; o1.y += pv*v1.y; o1.z += pv*v1.z; o1.w += pv*v1.w;
      o2.x += pv*v2.x; o2.y += pv*v2.y; o2.z += pv*v2.z; o2.w += pv*v2.w;
    }
    float* orow = qkv + (size_t)(b*S_ + i)*288 + h4*48 + hb;
    o0.x *= inv; o0.y *= inv; o0.z *= inv; o0.w *= inv;
    o1.x *= inv; o1.y *= inv; o1.z *= inv; o1.w *= inv;
    o2.x *= inv; o2.y *= inv; o2.z *= inv; o2.w *= inv;
    *(float4*)&orow[0] = o0;
    *(float4*)&orow[4] = o1;
    *(float4*)&orow[8] = o2;
  }
}

// ---------------- Wo-proj via bf16 MFMA + residual epilogue -> preLN (cols 144..239) ----
__global__ __launch_bounds__(256) void k_wo_mfma(float* __restrict__ scratch_base,
                                                 const unsigned short* __restrict__ wo_b,
                                                 const float* __restrict__ bo_b,
                                                 const float* __restrict__ x)
{
  int l = blockIdx.y;
  float* scr = scratch_base + (size_t)l*SCR_L;
  const unsigned short* Ab = (const unsigned short*)scr;   // row stride 576, offset 192
  const unsigned short* wb = wo_b + (size_t)l*96*96;
  const float* bo = bo_b + (size_t)l*96;

  int tid = threadIdx.x;
  int wv = tid >> 6, lane = tid & 63;
  int c = lane & 15, g = lane >> 4;
  int row0 = blockIdx.x*64 + wv*16;

  short8v afrag[3];
  const unsigned short* arow = Ab + (size_t)(row0 + c)*576 + 192 + g*8;
  #pragma unroll
  for (int kc = 0; kc < 3; kc++) afrag[kc] = *(const short8v*)&arow[kc*32];

  for (int ct = 0; ct < 6; ct++) {
    int col0 = ct*16;
    short8v bfrag[3];
    const unsigned short* wrow = wb + (size_t)(col0 + c)*96 + g*8;
    #pragma unroll
    for (int kc = 0; kc < 3; kc++) bfrag[kc] = *(const short8v*)&wrow[kc*32];
    float4v acc = {0.f, 0.f, 0.f, 0.f};
    #pragma unroll
    for (int kc = 0; kc < 3; kc++)
      acc = __builtin_amdgcn_mfma_f32_16x16x32_bf16(afrag[kc], bfrag[kc], acc, 0, 0, 0);
    float bj = bo[col0 + c];
    #pragma unroll
    for (int reg = 0; reg < 4; reg++) {
      int row = row0 + g*4 + reg;
      scr[(size_t)row*288 + 144 + col0 + c] = acc[reg] + bj + x[(size_t)row*96 + col0 + c];
    }
  }
}

// ---------------- LN(n1) over preLN (cols 144..239) -> normalized bf16 (ushort 480..575) ----
__global__ __launch_bounds__(256) void k_lnbf16(float* __restrict__ scratch_base,
                                                const float* __restrict__ n1g_b,
                                                const float* __restrict__ n1b_b)
{
  int l = blockIdx.y;
  float* scr = scratch_base + (size_t)l*SCR_L;
  const float* g = n1g_b + (size_t)l*96;
  const float* bb = n1b_b + (size_t)l*96;
  int row = blockIdx.x*4 + (threadIdx.x >> 6);
  int t = threadIdx.x & 63;
  const float* in = scr + (size_t)row*288 + 144;
  float e0 = in[t];
  float e1 = (t < 32) ? in[64 + t] : 0.f;
  float s = e0 + e1;
  for (int off = 32; off > 0; off >>= 1) s += __shfl_xor(s, off, 64);
  float mean = s * (1.f/96.f);
  float d0 = e0 - mean;
  float d1 = (t < 32) ? (e1 - mean) : 0.f;
  float v = d0*d0 + d1*d1;
  for (int off = 32; off > 0; off >>= 1) v += __shfl_xor(v, off, 64);
  float rstd = rsqrtf(v*(1.f/96.f) + 1e-5f);
  unsigned short* outp = (unsigned short*)scr + (size_t)row*576 + 480;
  outp[t] = f2bf(d0*rstd*g[t] + bb[t]);
  if (t < 32) outp[64 + t] = f2bf(d1*rstd*g[64 + t] + bb[64 + t]);
}

// ---------------- KV-proj via bf16 MFMA: normalized bf16 -> kv fp32 ----------------
__global__ __launch_bounds__(256) void k_kv_mfma(const float* __restrict__ scratch_base,
                                                 const unsigned short* __restrict__ kwi_full, // [3][288][96] bf16
                                                 const float* __restrict__ ci_bi_b,
                                                 float* __restrict__ kv_base)
{
  int l = blockIdx.y;
  const float* scr = scratch_base + (size_t)l*SCR_L;
  const unsigned short* Ab = (const unsigned short*)scr;   // row stride 576, offset 480
  const unsigned short* kwi = kwi_full + (size_t)l*288*96 + 96*96;
  const float* kbi = ci_bi_b + (size_t)l*288 + 96;
  float* out = kv_base + (size_t)l*KV_L;

  int tid = threadIdx.x;
  int wv = tid >> 6, lane = tid & 63;
  int c = lane & 15, g = lane >> 4;
  int row0 = blockIdx.x*64 + wv*16;

  short8v afrag[3];
  const unsigned short* arow = Ab + (size_t)(row0 + c)*576 + 480 + g*8;
  #pragma unroll
  for (int kc = 0; kc < 3; kc++) afrag[kc] = *(const short8v*)&arow[kc*32];

  for (int ct = 0; ct < 12; ct++) {
    int col0 = ct*16;
    short8v bfrag[3];
    const unsigned short* wrow = kwi + (size_t)(col0 + c)*96 + g*8;
    #pragma unroll
    for (int kc = 0; kc < 3; kc++) bfrag[kc] = *(const short8v*)&wrow[kc*32];
    float4v acc = {0.f, 0.f, 0.f, 0.f};
    #pragma unroll
    for (int kc = 0; kc < 3; kc++)
      acc = __builtin_amdgcn_mfma_f32_16x16x32_bf16(afrag[kc], bfrag[kc], acc, 0, 0, 0);
    float bj = kbi[col0 + c];
    #pragma unroll
    for (int reg = 0; reg < 4; reg++)
      out[(size_t)(row0 + g*4 + reg)*192 + col0 + c] = acc[reg] + bj;
  }
}

// ---------------- tiled GEMM (head1 only) ----------------
template<int ACT>
__global__ __launch_bounds__(256) void k_gemm96(const float* __restrict__ A,
                                                const float* __restrict__ W,
                                                const float* __restrict__ bias,
                                                float* __restrict__ out,
                                                int nrows, int out_dim)
{
  __shared__ __align__(16) float a_s[32*100];
  __shared__ __align__(16) float w_s[128*100];
  __shared__ float b_s[128];
  int tid = threadIdx.x;
  int row0 = blockIdx.x*32, col0 = blockIdx.y*128;
  for (int idx = tid; idx < 32*24; idx += 256) {
    int r = idx/24, q = idx%24;
    *(float4*)&a_s[r*100 + q*4] = *(const float4*)&A[(size_t)(row0+r)*96 + q*4];
  }
  for (int idx = tid; idx < 128*24; idx += 256) {
    int j = idx/24, q = idx%24;
    int jj = col0 + j;
    float4 w;
    if (jj < out_dim) w = *(const float4*)&W[(size_t)jj*96 + q*4];
    else { w.x = w.y = w.z = w.w = 0.f; }
    *(float4*)&w_s[j*100 + q*4] = w;
  }
  if (tid < 128) b_s[tid] = (col0 + tid < out_dim) ? bias[col0 + tid] : 0.f;
  __syncthreads();
  int tc = tid % 32, tr = tid / 32;
  int r0 = tr*4;
  float acc[4][4];
  #pragma unroll
  for (int cc = 0; cc < 4; cc++) {
    float bv = b_s[tc + 32*cc];
    #pragma unroll
    for (int rr = 0; rr < 4; rr++) acc[rr][cc] = bv;
  }
  #pragma unroll
  for (int d = 0; d < 96; d += 4) {
    float4 a4[4], w4[4];
    #pragma unroll
    for (int rr = 0; rr < 4; rr++) a4[rr] = *(float4*)&a_s[(r0+rr)*100 + d];
    #pragma unroll
    for (int cc = 0; cc < 4; cc++) w4[cc] = *(float4*)&w_s[(tc + 32*cc)*100 + d];
    #pragma unroll
    for (int rr = 0; rr < 4; rr++)
      #pragma unroll
      for (int cc = 0; cc < 4; cc++)
        acc[rr][cc] += dot4f(a4[rr], w4[cc]);
  }
  #pragma unroll
  for (int rr = 0; rr < 4; rr++) {
    int row = row0 + r0 + rr;
    float* orow = out + (size_t)row*out_dim + col0;
    #pragma unroll
    for (int cc = 0; cc < 4; cc++) {
      int j = tc + 32*cc;
      if (col0 + j < out_dim) {
        float v = acc[rr][cc];
        if (ACT == 1) v = geluf(v);
        orow[j] = v;
      }
    }
  }
}

// ---------------- logits GEMM via bf16 MFMA (R20-validated) ----------------
__global__ __launch_bounds__(256) void k_logits_mfma(const unsigned short* __restrict__ Ab,
                                                     const unsigned short* __restrict__ Wb,
                                                     const float* __restrict__ bias,
                                                     float* __restrict__ out)
{
  int tid = threadIdx.x;
  int wv = tid >> 6, lane = tid & 63;
  int col0 = blockIdx.x*64 + wv*16;
  int c = lane & 15, g = lane >> 4;

  short8v bfrag[3];
  const unsigned short* wrow = Wb + (size_t)(col0 + c)*96 + g*8;
  #pragma unroll
  for (int kc = 0; kc < 3; kc++)
    bfrag[kc] = *(const short8v*)&wrow[kc*32];
  float bj = bias[col0 + c];

  for (int rt = 0; rt < 64; rt++) {
    const unsigned short* arow = Ab + (size_t)(rt*16 + c)*96 + g*8;
    float4v acc = {0.f, 0.f, 0.f, 0.f};
    #pragma unroll
    for (int kc = 0; kc < 3; kc++) {
      short8v afrag = *(const short8v*)&arow[kc*32];
      acc = __builtin_amdgcn_mfma_f32_16x16x32_bf16(afrag, bfrag[kc], acc, 0, 0, 0);
    }
    int row = rt*16 + g*4;
    #pragma unroll
    for (int reg = 0; reg < 4; reg++)
      out[(size_t)(row + reg)*V_ + col0 + c] = acc[reg] + bj;
  }
}

// ---------------- one full recurrent step, SR_ batch rows per block (R12 proven) ----------------
__global__ __launch_bounds__(256) void k_step(float* __restrict__ hidden,
    const float* __restrict__ kv_l,
    const float* __restrict__ ci_wi, const float* __restrict__ ci_bi,
    const float* __restrict__ ci_wo, const float* __restrict__ ci_bo,
    const float* __restrict__ ch_wi, const float* __restrict__ ch_bi,
    const float* __restrict__ ch_wo, const float* __restrict__ ch_bo,
    const float* __restrict__ gw, const float* __restrict__ gb,
    const float* __restrict__ w1, const float* __restrict__ b1,
    const float* __restrict__ w2, const float* __restrict__ b2,
    const float* __restrict__ n2g, const float* __restrict__ n2b,
    const float* __restrict__ n3g, const float* __restrict__ n3b)
{
  __shared__ __align__(16) float hs[SR_][100];
  __shared__ __align__(16) float bufA[SR_][100];
  __shared__ __align__(16) float bufB[SR_][100];
  __shared__ __align__(16) float bufC[SR_][100];
  __shared__ __align__(16) float f1b[SR_][200];
  int tid = threadIdx.x; int b0 = blockIdx.x*SR_;

  for (int idx = tid; idx < SR_*24; idx += 256) {
    int r = idx/24, q = idx%24;
    *(float4*)&hs[r][q*4] = *(const float4*)&hidden[(size_t)(b0+r)*96 + q*4];
  }
  __syncthreads();

  for (int idx = tid; idx < SR_*192; idx += 256) {
    int r = idx % SR_, j = idx / SR_;
    const float* wr = (j < 96) ? (ci_wi + (size_t)j*96) : (ch_wi + (size_t)(96 + j)*96);
    float acc = (j < 96) ? ci_bi[j] : ch_bi[96 + j];
    #pragma unroll
    for (int d = 0; d < 96; d += 4) {
      float4 a = *(float4*)&hs[r][d];
      float4 w = *(const float4*)&wr[d];
      acc += dot4f(a, w);
    }
    if (j < 96) bufA[r][j] = acc; else bufB[r][j-96] = acc;
  }
  __syncthreads();

  if (tid < SR_*8) {
    int r = tid >> 3, h = tid & 7;
    int b = b0 + r;
    float q[12];
    #pragma unroll
    for (int d = 0; d < 12; d++) q[d] = bufA[r][h*12 + d];
    float p[50]; float mx = -1e30f;
    for (int s = 0; s < 50; s++) {
      const float* kr = kv_l + ((size_t)(b*50 + s))*192 + h*12;
      float4 k0 = *(const float4*)&kr[0];
      float4 k1 = *(const float4*)&kr[4];
      float4 k2 = *(const float4*)&kr[8];
      float acc = q[0]*k0.x + q[1]*k0.y + q[2]*k0.z + q[3]*k0.w
                + q[4]*k1.x + q[5]*k1.y + q[6]*k1.z + q[7]*k1.w
                + q[8]*k2.x + q[9]*k2.y + q[10]*k2.z + q[11]*k2.w;
      acc *= 0.28867513459481287f;
      p[s] = acc; mx = fmaxf(mx, acc);
    }
    float sum = 0.f;
    for (int s = 0; s < 50; s++) { p[s] = expf(p[s] - mx); sum += p[s]; }
    float inv = 1.f / sum;
    float o[12];
    #pragma unroll
    for (int d = 0; d < 12; d++) o[d] = 0.f;
    for (int s = 0; s < 50; s++) {
      const float* vr = kv_l + ((size_t)(b*50 + s))*192 + 96 + h*12;
      float4 v0 = *(const float4*)&vr[0];
      float4 v1 = *(const float4*)&vr[4];
      float4 v2 = *(const float4*)&vr[8];
      float pv = p[s];
      o[0] += pv*v0.x; o[1] += pv*v0.y; o[2]  += pv*v0.z; o[3]  += pv*v0.w;
      o[4] += pv*v1.x; o[5] += pv*v1.y; o[6]  += pv*v1.z; o[7]  += pv*v1.w;
      o[8] += pv*v2.x; o[9] += pv*v2.y; o[10] += pv*v2.z; o[11] += pv*v2.w;
    }
    #pragma unroll
    for (int d = 0; d < 12; d++) bufC[r][h*12 + d] = o[d]*inv;
  }
  __syncthreads();

  for (int idx = tid; idx < SR_*192; idx += 256) {
    int r = idx % SR_, j = idx / SR_;
    int jj = (j < 96) ? j : (j - 96);
    const float* ar = (j < 96) ? bufC[r] : bufB[r];
    const float* wr = ((j < 96) ? ci_wo : ch_wo) + (size_t)jj*96;
    float acc = (j < 96) ? ci_bo[jj] : ch_bo[jj];
    #pragma unroll
    for (int d = 0; d < 96; d += 4) {
      float4 a = *(float4*)&ar[d];
      float4 w = *(const float4*)&wr[d];
      acc += dot4f(a, w);
    }
    if (j < 96) bufA[r][j] = acc; else f1b[r][jj] = acc;
  }
  __syncthreads();

  for (int idx = tid; idx < SR_*96; idx += 256) {
    int r = idx % SR_, j = idx / SR_;
    const float* gr = gw + (size_t)j*192;
    float acc = gb[j];
    #pragma unroll
    for (int d = 0; d < 96; d += 4) {
      float4 c1v = *(float4*)&bufA[r][d];
      float4 g1 = *(const float4*)&gr[d];
      float4 c2v = *(float4*)&f1b[r][d];
      float4 g2 = *(const float4*)&gr[96 + d];
      acc += dot4f(c1v, g1) + dot4f(c2v, g2);
    }
    float gv = 1.f/(1.f + expf(-acc));
    float pre = gv*bufA[r][j] + (1.f - gv)*f1b[r][j] + hs[r][j];
    bufB[r][j] = pre;
  }
  __syncthreads();
  if (tid < SR_*16) {
    int r = tid / 16, l16 = tid % 16;
    float s1 = 0.f, s2 = 0.f;
    #pragma unroll
    for (int e = 0; e < 6; e++) { float v = bufB[r][l16*6 + e]; s1 += v; s2 += v*v; }
    for (int off = 8; off > 0; off >>= 1) { s1 += __shfl_xor(s1, off, 16); s2 += __shfl_xor(s2, off, 16); }
    float mean = s1*(1.f/96.f);
    float var = s2*(1.f/96.f) - mean*mean;
    float rstd = rsqrtf(var + 1e-5f);
    #pragma unroll
    for (int e = 0; e < 6; e++) {
      int j = l16*6 + e;
      bufB[r][j] = (bufB[r][j] - mean)*rstd*n2g[j] + n2b[j];
    }
  }
  __syncthreads();

  for (int idx = tid; idx < SR_*192; idx += 256) {
    int r = idx % SR_, j = idx / SR_;
    const float* wr = w1 + (size_t)j*96;
    float acc = b1[j];
    #pragma unroll
    for (int d = 0; d < 96; d += 4) {
      float4 a = *(float4*)&bufB[r][d];
      float4 w = *(const float4*)&wr[d];
      acc += dot4f(a, w);
    }
    f1b[r][j] = geluf(acc);
  }
  __syncthreads();

  for (int idx = tid; idx < SR_*96; idx += 256) {
    int r = idx % SR_, j = idx / SR_;
    const float* wr = w2 + (size_t)j*192;
    float acc = b2[j];
    #pragma unroll
    for (int d = 0; d < 192; d += 4) {
      float4 a = *(float4*)&f1b[r][d];
      float4 w = *(const float4*)&wr[d];
      acc += dot4f(a, w);
    }
    bufC[r][j] = acc + bufB[r][j];
  }
  __syncthreads();
  if (tid < SR_*16) {
    int r = tid / 16, l16 = tid % 16;
    float s1 = 0.f, s2 = 0.f;
    #pragma unroll
    for (int e = 0; e < 6; e++) { float v = bufC[r][l16*6 + e]; s1 += v; s2 += v*v; }
    for (int off = 8; off > 0; off >>= 1) { s1 += __shfl_xor(s1, off, 16); s2 += __shfl_xor(s2, off, 16); }
    float mean = s1*(1.f/96.f);
    float var = s2*(1.f/96.f) - mean*mean;
    float rstd = rsqrtf(var + 1e-5f);
    #pragma unroll
    for (int e = 0; e < 6; e++) {
      int j = l16*6 + e;
      hidden[(size_t)(b0 + r)*96 + j] = (bufC[r][j] - mean)*rstd*n3g[j] + n3b[j];
    }
  }
}

extern "C" void kernel_launch(void* const* d_in, const int* in_sizes, int n_in,
                              void* d_out, int out_size, void* d_ws, size_t ws_size,
                              hipStream_t stream) {
  (void)in_sizes; (void)n_in; (void)out_size; (void)ws_size;
  const int* locations   = (const int*)d_in[0];
  const int* users       = (const int*)d_in[1];
  const int* start_mins  = (const int*)d_in[2];
  const int* weekdays    = (const int*)d_in[3];
  const float* loc_emb   = (const float*)d_in[4];
  const float* user_emb  = (const float*)d_in[5];
  const float* hour_emb  = (const float*)d_in[6];
  const float* wd_emb    = (const float*)d_in[7];
  const float* temp_w    = (const float*)d_in[8];
  const float* temp_b    = (const float*)d_in[9];
  const float* pos_embed = (const float*)d_in[10];
  const float* init_hidden = (const float*)d_in[11];
  const float* out_w1    = (const float*)d_in[12];
  const float* out_b1    = (const float*)d_in[13];
  const float* out_w2    = (const float*)d_in[14];
  const float* out_b2    = (const float*)d_in[15];
  const float* sa_wi = (const float*)d_in[16];
  const float* sa_bi = (const float*)d_in[17];
  const float* sa_wo = (const float*)d_in[18];
  const float* sa_bo = (const float*)d_in[19];
  const float* ci_wi = (const float*)d_in[20];
  const float* ci_bi = (const float*)d_in[21];
  const float* ci_wo = (const float*)d_in[22];
  const float* ci_bo = (const float*)d_in[23];
  const float* ch_wi = (const float*)d_in[24];
  const float* ch_bi = (const float*)d_in[25];
  const float* ch_wo = (const float*)d_in[26];
  const float* ch_bo = (const float*)d_in[27];
  const float* ffn_w1 = (const float*)d_in[28];
  const float* ffn_b1 = (const float*)d_in[29];
  const float* ffn_w2 = (const float*)d_in[30];
  const float* ffn_b2 = (const float*)d_in[31];
  const float* gate_w = (const float*)d_in[32];
  const float* gate_b = (const float*)d_in[33];
  const float* n1_g = (const float*)d_in[34];
  const float* n1_b = (const float*)d_in[35];
  const float* n2_g = (const float*)d_in[36];
  const float* n2_b = (const float*)d_in[37];
  const float* n3_g = (const float*)d_in[38];
  const float* n3_b = (const float*)d_in[39];

  float* ws = (float*)d_ws;
  float* x       = ws;                           // 4,915,200
  float* scratch = x + 4915200;                  // 3 * 14,745,600 (dead after phase A)
  float* kv      = scratch + 3ull*SCR_L;         // 29,491,200
  float* hidden  = kv + 29491200;                // 98,304
  float* h1      = hidden + 98304;               // 98,304

  // bf16 staging: x/sa_wi in kv region (dead until k_kv_mfma writes kv — consumed before)
  unsigned short* xb2 = (unsigned short*)kv;               // 4,915,200 bf16
  unsigned short* wib = xb2 + 4915200;                     // 3*288*96 bf16
  // small weight stages in h1 region (dead until head)
  unsigned short* wo_b  = (unsigned short*)h1;             // 3*96*96 = 27,648 bf16
  unsigned short* kwi_b = wo_b + 27648;                    // 3*288*96 = 82,944 bf16
  // head bf16 staging in scratch region (dead after phase A)
  unsigned short* h1b = (unsigned short*)scratch;          // 98,304 bf16
  unsigned short* w2b = h1b + 98304;                       // 3,840,000 bf16

  k_embed<<<B_*S_, 96, 0, stream>>>(locations, users, start_mins, weekdays,
                                    loc_emb, user_emb, hour_emb, wd_emb,
                                    temp_w, temp_b, pos_embed, x);
  k_init<<<(B_*D_ + 255)/256, 256, 0, stream>>>(init_hidden, hidden);

  // Phase A (all layers batched via blockIdx.y, full MFMA pipeline)
  k_tobf16<<<(B_*S_*D_ + 255)/256, 256, 0, stream>>>(x, xb2, B_*S_*D_);
  k_tobf16<<<(3*288*96 + 255)/256, 256, 0, stream>>>(sa_wi, wib, 3*288*96);
  k_tobf16<<<(3*96*96 + 255)/256, 256, 0, stream>>>(sa_wo, wo_b, 3*96*96);
  k_tobf16<<<(3*288*96 + 255)/256, 256, 0, stream>>>(ci_wi, kwi_b, 3*288*96);
  k_qkv_mfma<<<dim3(800, 3), 256, 0, stream>>>(xb2, wib, sa_bi, scratch);
  k_attn3<<<dim3(2048, 3), 256, 0, stream>>>(scratch);
  k_tobf16_attn<<<dim3(19200, 3), 256, 0, stream>>>(scratch);
  k_wo_mfma<<<dim3(800, 3), 256, 0, stream>>>(scratch, wo_b, sa_bo, x);
  k_lnbf16<<<dim3(12800, 3), 256, 0, stream>>>(scratch, n1_g, n1_b);
  k_kv_mfma<<<dim3(800, 3), 256, 0, stream>>>(scratch, kwi_b, ci_bi, kv);

  // Phase B: 9 separate recurrent steps (R12-measured best)
  for (int c = 0; c < NC_; c++) {
    for (int l = 0; l < L_; l++) {
      k_step<<<B_/SR_, 256, 0, stream>>>(hidden, kv + (size_t)l*KV_L,
          ci_wi + (size_t)l*288*96, ci_bi + l*288,
          ci_wo + (size_t)l*96*96,  ci_bo + l*96,
          ch_wi + (size_t)l*288*96, ch_bi + l*288,
          ch_wo + (size_t)l*96*96,  ch_bo + l*96,
          gate_w + (size_t)l*96*192, gate_b + l*96,
          ffn_w1 + (size_t)l*192*96, ffn_b1 + l*192,
          ffn_w2 + (size_t)l*96*192, ffn_b2 + l*96,
          n2_g + l*96, n2_b + l*96, n3_g + l*96, n3_b + l*96);
    }
  }

  // Head: h1 (fp32) -> bf16, W2 -> bf16, logits via MFMA (R20-validated)
  k_gemm96<1><<<dim3(B_/32, 1), 256, 0, stream>>>(hidden, out_w1, out_b1, h1, B_, 96);
  k_tobf16<<<(B_*D_ + 255)/256, 256, 0, stream>>>(h1, h1b, B_*D_);
  k_tobf16<<<(V_*D_ + 255)/256, 256, 0, stream>>>(out_w2, w2b, V_*D_);
  k_logits_mfma<<<V_/64, 256, 0, stream>>>(h1b, w2b, out_b2, (float*)d_out);
}